// Round 8
// baseline (337.430 us; speedup 1.0000x reference)
//
#include <hip/hip_runtime.h>

#define NN 2048       // nodes per batch
#define FF 128        // features per node
#define KK 16         // top-K
#define MASKROWS 1024 // rows >= 1024 never active (tau <= 1023)
#define INF_KEY 0xFFFFFFFFFFFFFFFFull

typedef float f32x4 __attribute__((ext_vector_type(4)));

// ---------- wave64 min-reduce via DPP (VALU pipe, no LDS/permute) ----------
__device__ __forceinline__ unsigned wave_min_u32(unsigned x) {
    int v = (int)x, t;
    t = __builtin_amdgcn_update_dpp(v, v, 0x111, 0xf, 0xf, false); // row_shr:1
    v = ((unsigned)t < (unsigned)v) ? t : v;
    t = __builtin_amdgcn_update_dpp(v, v, 0x112, 0xf, 0xf, false); // row_shr:2
    v = ((unsigned)t < (unsigned)v) ? t : v;
    t = __builtin_amdgcn_update_dpp(v, v, 0x114, 0xf, 0xf, false); // row_shr:4
    v = ((unsigned)t < (unsigned)v) ? t : v;
    t = __builtin_amdgcn_update_dpp(v, v, 0x118, 0xf, 0xf, false); // row_shr:8
    v = ((unsigned)t < (unsigned)v) ? t : v;
    t = __builtin_amdgcn_update_dpp(v, v, 0x142, 0xf, 0xf, false); // row_bcast:15
    v = ((unsigned)t < (unsigned)v) ? t : v;
    t = __builtin_amdgcn_update_dpp(v, v, 0x143, 0xf, 0xf, false); // row_bcast:31
    v = ((unsigned)t < (unsigned)v) ? t : v;
    return (unsigned)__builtin_amdgcn_readlane(v, 63);
}

__device__ __forceinline__ f32x4 load_xyz(const float* __restrict__ nodes_b, int idx) {
    const float* p = nodes_b + (size_t)idx * FF;
    return (f32x4){p[0], p[1], p[2], 0.f};   // same float bits as reference
}

// Kernel 1: selection only. One block = 4 rows (4 waves); rows >= 1024 never
// active so grid.y = 256. Verified one-pass per-lane sorted top-4 queue + 16
// DPP extraction rounds (R0/R1/R4/R5-verified, byte-identical) -> 64-word
// column bitmask per row into the 4 MB workspace mask. No dense writes.
__global__ __launch_bounds__(256, 8) void knn_mask(
    const float* __restrict__ nodes,
    const int*   __restrict__ T_arr,
    const int*   __restrict__ tau_arr,
    unsigned*    __restrict__ mask)
{
    const int b    = blockIdx.x;
    const int i0   = blockIdx.y << 2;
    const int wave = threadIdx.x >> 6;
    const int lane = threadIdx.x & 63;

    const int tau = tau_arr[b];
    if (i0 >= tau) return;                    // inactive rows: writer emits zeros

    const int i = i0 + wave;
    if (i >= tau) return;

    const int T = T_arr[b];
    const int M = T + tau;                    // src_valid: j < M (<= 2046)
    const float* base = nodes + (size_t)b * NN * FF;

    const int g = T + i;                      // sink global index (< M always)
    const f32x4 sp = load_xyz(base, g);
    const float sxv = sp.x, syv = sp.y, szv = sp.z;

    // ---- one-pass build of per-lane sorted top-4 queue ----
    unsigned long long q0 = INF_KEY, q1 = INF_KEY, q2 = INF_KEY, q3 = INF_KEY;
    const int S = (M + 63) >> 6;
    #pragma unroll 4
    for (int s = 0; s < S; ++s) {
        const int j = lane + (s << 6);
        if (j < M) {
            const f32x4 v = load_xyz(base, j);
            float dx = __fsub_rn(sxv, v.x);
            float dy = __fsub_rn(syv, v.y);
            float dz = __fsub_rn(szv, v.z);
            float d2 = __fadd_rn(__fadd_rn(__fmul_rn(dx, dx), __fmul_rn(dy, dy)),
                                 __fmul_rn(dz, dz));
            unsigned long long key =
                ((unsigned long long)__float_as_uint(d2) << 32) | (unsigned)(j + 1);
            if (key < q3) {
                q3 = key;
                unsigned long long t;
                if (q3 < q2) { t = q2; q2 = q3; q3 = t; }
                if (q2 < q1) { t = q1; q1 = q2; q2 = t; }
                if (q1 < q0) { t = q0; q0 = q1; q1 = t; }
            }
        }
    }

    // ---- 16 extraction rounds: DPP min on head d2 + ballot index resolve ----
    unsigned colmask = 0;                     // this lane's cols [32*lane, +32)
    unsigned long long lastpop = 0;
    for (int k = 0; k < KK; ++k) {
        const unsigned hd = (unsigned)(q0 >> 32);
        const unsigned m  = wave_min_u32(hd);
        if (m == 0xFFFFFFFFu) break;          // all lanes exhausted

        const unsigned long long bmask = __ballot(hd == m);
        unsigned jwin;
        if (__popcll(bmask) == 1) {           // unique head d2 (common case)
            const int w = __builtin_ctzll(bmask);
            jwin = (unsigned)__builtin_amdgcn_readlane((int)(unsigned)q0, w);
        } else {                              // cross-lane d2 tie (rare)
            unsigned jc = (hd == m) ? (unsigned)q0 : 0xFFFFFFFFu;
            jwin = wave_min_u32(jc);
        }
        const int j = (int)jwin - 1;

        if (j < i && (j >> 5) == lane)        // causal + word ownership
            colmask |= 1u << (j & 31);

        if (hd == m && (unsigned)q0 == jwin) {  // pop on the winner lane
            lastpop = ((unsigned long long)m << 32) | jwin;
            q0 = q1; q1 = q2; q2 = q3; q3 = INF_KEY;
            if (q0 == INF_KEY) {              // rare: >4 global hits this lane
                unsigned long long best = INF_KEY;
                for (int s2 = 0; s2 < S; ++s2) {
                    const int jj = lane + (s2 << 6);
                    if (jj < M) {
                        const f32x4 v = load_xyz(base, jj);
                        float dx = __fsub_rn(sxv, v.x);
                        float dy = __fsub_rn(syv, v.y);
                        float dz = __fsub_rn(szv, v.z);
                        float d2 = __fadd_rn(
                            __fadd_rn(__fmul_rn(dx, dx), __fmul_rn(dy, dy)),
                            __fmul_rn(dz, dz));
                        unsigned long long kk =
                            ((unsigned long long)__float_as_uint(d2) << 32)
                            | (unsigned)(jj + 1);
                        if (kk > lastpop && kk < best) best = kk;
                    }
                }
                q0 = best;
            }
        }
    }

    // one word per lane; word w covers cols [32w, 32w+32) -> R0-verified map
    mask[((size_t)(b * MASKROWS + i) << 6) + lane] = colmask;
}

// Kernel 2: pure streaming writer. Reads the 4 MB mask (L2-hot), expands to
// 0.0/1.0, NT-stores the whole 268 MB output — structurally the same access
// pattern as the 6.2 TB/s fill kernel. Inactive rows (i >= tau, incl. all
// i >= 1024) write zeros without touching the mask.
__global__ __launch_bounds__(256) void write_adj(
    const unsigned* __restrict__ mask,
    const int*      __restrict__ tau_arr,
    float*          __restrict__ adj)
{
    const int b    = blockIdx.x;
    const int i0   = blockIdx.y << 2;
    const int wave = threadIdx.x >> 6;
    const int lane = threadIdx.x & 63;

    const int tau = tau_arr[b];
    const int i   = i0 + wave;
    f32x4* out4 = (f32x4*)(adj + ((size_t)b * NN + i) * NN);

    if (i >= tau) {                           // inactive row: stream zeros
        const f32x4 z = (f32x4){0.f, 0.f, 0.f, 0.f};
        #pragma unroll
        for (int k = 0; k < 8; ++k)
            __builtin_nontemporal_store(z, &out4[(k << 6) + lane]);
        return;
    }

    const unsigned* mrow = mask + ((size_t)(b * MASKROWS + i) << 6);
    #pragma unroll
    for (int k = 0; k < 8; ++k) {
        // chunk = 64k + lane covers cols [4*chunk, 4*chunk+4)
        const unsigned w   = mrow[(k << 3) + (lane >> 3)];
        const unsigned nib = (w >> ((lane & 7) << 2)) & 0xFu;
        f32x4 v;
        v.x = (nib & 1u) ? 1.0f : 0.0f;
        v.y = (nib & 2u) ? 1.0f : 0.0f;
        v.z = (nib & 4u) ? 1.0f : 0.0f;
        v.w = (nib & 8u) ? 1.0f : 0.0f;
        __builtin_nontemporal_store(v, &out4[(k << 6) + lane]);
    }
}

// Fallback (tiny/absent workspace): verified R5 structure — memset + direct
// scatter of single 1.0 stores (312 us, correct). Only used if ws < 4 MB.
__global__ __launch_bounds__(256, 8) void knn_scatter_direct(
    const float* __restrict__ nodes,
    const int*   __restrict__ T_arr,
    const int*   __restrict__ tau_arr,
    float*       __restrict__ adj)
{
    const int b    = blockIdx.x;
    const int i0   = blockIdx.y << 2;
    const int wave = threadIdx.x >> 6;
    const int lane = threadIdx.x & 63;

    const int tau = tau_arr[b];
    if (i0 >= tau) return;
    const int i = i0 + wave;
    if (i >= tau) return;

    const int T = T_arr[b];
    const int M = T + tau;
    const float* base = nodes + (size_t)b * NN * FF;
    float* row = adj + ((size_t)b * NN + i) * NN;

    const int g = T + i;
    const f32x4 sp = load_xyz(base, g);
    const float sxv = sp.x, syv = sp.y, szv = sp.z;

    unsigned long long q0 = INF_KEY, q1 = INF_KEY, q2 = INF_KEY, q3 = INF_KEY;
    const int S = (M + 63) >> 6;
    #pragma unroll 4
    for (int s = 0; s < S; ++s) {
        const int j = lane + (s << 6);
        if (j < M) {
            const f32x4 v = load_xyz(base, j);
            float dx = __fsub_rn(sxv, v.x);
            float dy = __fsub_rn(syv, v.y);
            float dz = __fsub_rn(szv, v.z);
            float d2 = __fadd_rn(__fadd_rn(__fmul_rn(dx, dx), __fmul_rn(dy, dy)),
                                 __fmul_rn(dz, dz));
            unsigned long long key =
                ((unsigned long long)__float_as_uint(d2) << 32) | (unsigned)(j + 1);
            if (key < q3) {
                q3 = key;
                unsigned long long t;
                if (q3 < q2) { t = q2; q2 = q3; q3 = t; }
                if (q2 < q1) { t = q1; q1 = q2; q2 = t; }
                if (q1 < q0) { t = q0; q0 = q1; q1 = t; }
            }
        }
    }

    unsigned long long lastpop = 0;
    for (int k = 0; k < KK; ++k) {
        const unsigned hd = (unsigned)(q0 >> 32);
        const unsigned m  = wave_min_u32(hd);
        if (m == 0xFFFFFFFFu) break;

        const unsigned long long bmask = __ballot(hd == m);
        unsigned jwin;
        if (__popcll(bmask) == 1) {
            const int w = __builtin_ctzll(bmask);
            jwin = (unsigned)__builtin_amdgcn_readlane((int)(unsigned)q0, w);
        } else {
            unsigned jc = (hd == m) ? (unsigned)q0 : 0xFFFFFFFFu;
            jwin = wave_min_u32(jc);
        }
        const int j = (int)jwin - 1;

        if (lane == 0 && j < i)
            row[j] = 1.0f;

        if (hd == m && (unsigned)q0 == jwin) {
            lastpop = ((unsigned long long)m << 32) | jwin;
            q0 = q1; q1 = q2; q2 = q3; q3 = INF_KEY;
            if (q0 == INF_KEY) {
                unsigned long long best = INF_KEY;
                for (int s2 = 0; s2 < S; ++s2) {
                    const int jj = lane + (s2 << 6);
                    if (jj < M) {
                        const f32x4 v = load_xyz(base, jj);
                        float dx = __fsub_rn(sxv, v.x);
                        float dy = __fsub_rn(syv, v.y);
                        float dz = __fsub_rn(szv, v.z);
                        float d2 = __fadd_rn(
                            __fadd_rn(__fmul_rn(dx, dx), __fmul_rn(dy, dy)),
                            __fmul_rn(dz, dz));
                        unsigned long long kk =
                            ((unsigned long long)__float_as_uint(d2) << 32)
                            | (unsigned)(jj + 1);
                        if (kk > lastpop && kk < best) best = kk;
                    }
                }
                q0 = best;
            }
        }
    }
}

extern "C" void kernel_launch(void* const* d_in, const int* in_sizes, int n_in,
                              void* d_out, int out_size, void* d_ws, size_t ws_size,
                              hipStream_t stream) {
    const float* nodes = (const float*)d_in[0];
    const int*   T     = (const int*)d_in[1];
    const int*   taus  = (const int*)d_in[2];
    float*       adj   = (float*)d_out;
    const int B = in_sizes[1];               // T has B elements (16)

    const size_t mask_bytes = (size_t)B * MASKROWS * 64 * sizeof(unsigned);

    if (d_ws != nullptr && ws_size >= mask_bytes) {
        // 1) selection -> 4 MB bitmask (no dense writes)
        knn_mask<<<dim3(B, MASKROWS / 4), dim3(256), 0, stream>>>(
            nodes, T, taus, (unsigned*)d_ws);
        // 2) pure streaming expand/write of all 268 MB
        write_adj<<<dim3(B, NN / 4), dim3(256), 0, stream>>>(
            (const unsigned*)d_ws, taus, adj);
    } else {                                 // fallback: R5-verified path
        const size_t out_bytes = (size_t)B * NN * NN * sizeof(float);
        hipMemsetAsync(adj, 0, out_bytes, stream);
        knn_scatter_direct<<<dim3(B, MASKROWS / 4), dim3(256), 0, stream>>>(
            nodes, T, taus, adj);
    }
}

// Round 9
// 276.669 us; speedup vs baseline: 1.2196x; 1.2196x over previous
//
#include <hip/hip_runtime.h>

#define NN 2048      // nodes per batch
#define FF 128       // features per node
#define KK 16        // top-K
#define INF_KEY 0xFFFFFFFFFFFFFFFFull

// ---------- wave64 min-reduce via DPP (VALU pipe, no LDS/permute) ----------
__device__ __forceinline__ unsigned wave_min_u32(unsigned x) {
    int v = (int)x, t;
    t = __builtin_amdgcn_update_dpp(v, v, 0x111, 0xf, 0xf, false); // row_shr:1
    v = ((unsigned)t < (unsigned)v) ? t : v;
    t = __builtin_amdgcn_update_dpp(v, v, 0x112, 0xf, 0xf, false); // row_shr:2
    v = ((unsigned)t < (unsigned)v) ? t : v;
    t = __builtin_amdgcn_update_dpp(v, v, 0x114, 0xf, 0xf, false); // row_shr:4
    v = ((unsigned)t < (unsigned)v) ? t : v;
    t = __builtin_amdgcn_update_dpp(v, v, 0x118, 0xf, 0xf, false); // row_shr:8
    v = ((unsigned)t < (unsigned)v) ? t : v;
    t = __builtin_amdgcn_update_dpp(v, v, 0x142, 0xf, 0xf, false); // row_bcast:15
    v = ((unsigned)t < (unsigned)v) ? t : v;
    t = __builtin_amdgcn_update_dpp(v, v, 0x143, 0xf, 0xf, false); // row_bcast:31
    v = ((unsigned)t < (unsigned)v) ? t : v;
    return (unsigned)__builtin_amdgcn_readlane(v, 63);
}

// Fused: one block = 4 rows of one batch. Inactive rows stream zeros (pure
// BW); active rows build a per-lane sorted top-4 queue of packed (d2,j+1)
// keys in one LDS pass (SoA sx/sy/sz: 2-way bank alias, free), extract the
// global top-16 with 32-bit DPP mins (exact refill covers >4-per-lane), and
// stream the 0/1 row via a 1 KB LDS word table (coalesced float4 stores).
// d2 uses strict-IEEE non-contracted ops; key order == numpy/jax top_k
// (d2, index) lexicographic order -> absmax 0 (verified R0..R8).
// Session ledger: fused = max(write-floor 43us, selection ~46us) + fixed
// ~60us harness overhead; every decoupled variant paid +45-60us of
// unoverlapped stream time (R1/R5/R8). This structure is the optimum.
__global__ __launch_bounds__(256) void knn_adj_fused(
    const float* __restrict__ nodes,
    const int*   __restrict__ T_arr,
    const int*   __restrict__ tau_arr,
    float*       __restrict__ adj)
{
    const int b    = blockIdx.x;
    const int i0   = blockIdx.y << 2;
    const int tid  = threadIdx.x;
    const int wave = tid >> 6;
    const int lane = tid & 63;

    const int tau = tau_arr[b];
    float* block_out = adj + ((size_t)b * NN + i0) * NN;

    if (i0 >= tau) {                          // whole block inactive: 32 KB zeros
        const float4 z = make_float4(0.f, 0.f, 0.f, 0.f);
        float4* out4 = (float4*)block_out;
        #pragma unroll
        for (int t = 0; t < 8; ++t)
            out4[tid + (t << 8)] = z;
        return;
    }

    const int T = T_arr[b];
    const int M = T + tau;                    // src_valid: j < M (<= 2046)

    __shared__ float sx[NN], sy[NN], sz[NN];  // 24 KiB, SoA: conflict-free
    __shared__ unsigned swords[4][64];        // 1 KiB: per-wave column words
    for (int j = tid; j < M; j += 256) {
        const float* p = nodes + ((size_t)b * NN + j) * FF;
        sx[j] = p[0];
        sy[j] = p[1];
        sz[j] = p[2];
    }
    __syncthreads();

    const int i = i0 + wave;
    float4* out4 = (float4*)(block_out + (size_t)wave * NN);

    if (i >= tau) {                           // inactive row in active block
        const float4 z = make_float4(0.f, 0.f, 0.f, 0.f);
        #pragma unroll
        for (int t = 0; t < 8; ++t)
            out4[(t << 6) + lane] = z;
        return;
    }

    const int g = T + i;                      // sink global index (< M always)
    const float sxv = sx[g], syv = sy[g], szv = sz[g];

    // ---- one-pass build of per-lane sorted top-4 queue ----
    unsigned long long q0 = INF_KEY, q1 = INF_KEY, q2 = INF_KEY, q3 = INF_KEY;
    const int S = (M + 63) >> 6;
    #pragma unroll 4
    for (int s = 0; s < S; ++s) {
        const int j = lane + (s << 6);
        if (j < M) {
            float dx = __fsub_rn(sxv, sx[j]);
            float dy = __fsub_rn(syv, sy[j]);
            float dz = __fsub_rn(szv, sz[j]);
            float d2 = __fadd_rn(__fadd_rn(__fmul_rn(dx, dx), __fmul_rn(dy, dy)),
                                 __fmul_rn(dz, dz));
            unsigned long long key =
                ((unsigned long long)__float_as_uint(d2) << 32) | (unsigned)(j + 1);
            if (key < q3) {
                q3 = key;
                unsigned long long t;
                if (q3 < q2) { t = q2; q2 = q3; q3 = t; }
                if (q2 < q1) { t = q1; q1 = q2; q2 = t; }
                if (q1 < q0) { t = q0; q0 = q1; q1 = t; }
            }
        }
    }

    // ---- 16 extraction rounds: DPP min on head d2 + ballot index resolve ----
    unsigned colmask = 0;                     // this lane's cols [32*lane, +32)
    unsigned long long lastpop = 0;
    for (int k = 0; k < KK; ++k) {
        const unsigned hd = (unsigned)(q0 >> 32);
        const unsigned m  = wave_min_u32(hd);
        if (m == 0xFFFFFFFFu) break;          // all lanes exhausted

        const unsigned long long mask = __ballot(hd == m);
        unsigned jwin;
        if (__popcll(mask) == 1) {            // unique head d2 (common case)
            const int w = __builtin_ctzll(mask);
            jwin = (unsigned)__builtin_amdgcn_readlane((int)(unsigned)q0, w);
        } else {                              // cross-lane d2 tie (rare)
            unsigned jc = (hd == m) ? (unsigned)q0 : 0xFFFFFFFFu;
            jwin = wave_min_u32(jc);
        }
        const int j = (int)jwin - 1;

        if (j < i && (j >> 5) == lane)        // causal + word ownership
            colmask |= 1u << (j & 31);

        if (hd == m && (unsigned)q0 == jwin) {  // pop on the winner lane
            lastpop = ((unsigned long long)m << 32) | jwin;
            q0 = q1; q1 = q2; q2 = q3; q3 = INF_KEY;
            if (q0 == INF_KEY) {              // rare: >4 global hits this lane
                unsigned long long best = INF_KEY;
                for (int s2 = 0; s2 < S; ++s2) {
                    const int jj = lane + (s2 << 6);
                    if (jj < M) {
                        float dx = __fsub_rn(sxv, sx[jj]);
                        float dy = __fsub_rn(syv, sy[jj]);
                        float dz = __fsub_rn(szv, sz[jj]);
                        float d2 = __fadd_rn(
                            __fadd_rn(__fmul_rn(dx, dx), __fmul_rn(dy, dy)),
                            __fmul_rn(dz, dz));
                        unsigned long long kk =
                            ((unsigned long long)__float_as_uint(d2) << 32)
                            | (unsigned)(jj + 1);
                        if (kk > lastpop && kk < best) best = kk;
                    }
                }
                q0 = best;
            }
        }
    }

    // ---- route words through LDS (same wave: no barrier), stream the row ----
    swords[wave][lane] = colmask;
    #pragma unroll
    for (int k = 0; k < 8; ++k) {
        // cols c = 256k + 4*lane .. +3 ; word = 8k + (lane>>3) (broadcast read)
        const unsigned w   = swords[wave][(k << 3) + (lane >> 3)];
        const unsigned nib = (w >> ((lane & 7) << 2)) & 0xFu;
        float4 v;
        v.x = (nib & 1u) ? 1.0f : 0.0f;
        v.y = (nib & 2u) ? 1.0f : 0.0f;
        v.z = (nib & 4u) ? 1.0f : 0.0f;
        v.w = (nib & 8u) ? 1.0f : 0.0f;
        out4[(k << 6) + lane] = v;
    }
}

extern "C" void kernel_launch(void* const* d_in, const int* in_sizes, int n_in,
                              void* d_out, int out_size, void* d_ws, size_t ws_size,
                              hipStream_t stream) {
    const float* nodes = (const float*)d_in[0];
    const int*   T     = (const int*)d_in[1];
    const int*   taus  = (const int*)d_in[2];
    float*       adj   = (float*)d_out;
    const int B = in_sizes[1];               // T has B elements (16)

    dim3 grid(B, NN / 4);                    // 16 x 512 blocks, 256 thr each
    knn_adj_fused<<<grid, dim3(256), 0, stream>>>(nodes, T, taus, adj);
}